// Round 1
// baseline (813.180 us; speedup 1.0000x reference)
//
#include <hip/hip_runtime.h>
#include <math.h>

#define BB 16
#define CC 1024
#define NN 16384
#define HID 128         // C / RATIO
#define SPLIT 2
#define CHALF (CC/SPLIT)

// ---------------- K1: per-(b,c) mean & max over N ----------------
__global__ __launch_bounds__(256) void k1_pool(const float* __restrict__ x,
                                               float* __restrict__ meanp,
                                               float* __restrict__ maxp) {
    const int row = blockIdx.x;                 // b*C + c
    const int tid = threadIdx.x;
    const float4* xr = (const float4*)(x + (size_t)row * NN);
    float s = 0.f, m = -INFINITY;
    #pragma unroll
    for (int i = 0; i < 16; ++i) {
        float4 v = xr[tid + i * 256];
        s += v.x + v.y + v.z + v.w;
        m = fmaxf(m, fmaxf(fmaxf(v.x, v.y), fmaxf(v.z, v.w)));
    }
    __shared__ float ss[4], sm[4];
    for (int off = 32; off > 0; off >>= 1) {
        s += __shfl_down(s, off, 64);
        m = fmaxf(m, __shfl_down(m, off, 64));
    }
    const int wave = tid >> 6, lane = tid & 63;
    if (lane == 0) { ss[wave] = s; sm[wave] = m; }
    __syncthreads();
    if (tid == 0) {
        float fs = ss[0] + ss[1] + ss[2] + ss[3];
        float fm = fmaxf(fmaxf(sm[0], sm[1]), fmaxf(sm[2], sm[3]));
        meanp[row] = fs * (1.0f / NN);
        maxp[row]  = fm;
    }
}

// ---------------- K2: shared MLP -> gate ----------------
__global__ __launch_bounds__(256) void k2_gate(const float* __restrict__ meanp,
                                               const float* __restrict__ maxp,
                                               const float* __restrict__ w1,
                                               const float* __restrict__ w2,
                                               float* __restrict__ gate) {
    const int b = blockIdx.x;
    const int tid = threadIdx.x;
    __shared__ float smv[CC], sxv[CC], hm[HID], hx[HID], h[HID];
    for (int c = tid; c < CC; c += 256) {
        smv[c] = meanp[b * CC + c];
        sxv[c] = maxp[b * CC + c];
    }
    __syncthreads();
    {
        const int r = tid & 127;
        const float* src = (tid < 128) ? smv : sxv;
        const float* w1r = w1 + (size_t)r * CC;
        float acc = 0.f;
        for (int c = 0; c < CC; ++c) acc = fmaf(w1r[c], src[c], acc);
        acc = fmaxf(acc, 0.f);                  // relu
        if (tid < 128) hm[r] = acc; else hx[r] = acc;
    }
    __syncthreads();
    if (tid < HID) h[tid] = hm[tid] + hx[tid];
    __syncthreads();
    for (int c = tid; c < CC; c += 256) {
        const float* w2r = w2 + (size_t)c * HID;
        float a = 0.f;
        #pragma unroll 8
        for (int r = 0; r < HID; ++r) a = fmaf(w2r[r], h[r], a);
        gate[b * CC + c] = 1.0f / (1.0f + expf(-a));  // sigmoid
    }
}

// ---------------- K3: spatial weighted sum/max over C (partials) ----------------
__global__ __launch_bounds__(256) void k3_spatial(const float* __restrict__ x,
                                                  const float* __restrict__ gate,
                                                  float* __restrict__ psum,
                                                  float* __restrict__ pmax) {
    const int chunk = blockIdx.x;   // 0..N/1024-1
    const int split = blockIdx.y;   // 0..SPLIT-1
    const int b     = blockIdx.z;   // 0..B-1
    const int tid = threadIdx.x;
    __shared__ float g[CHALF];
    for (int i = tid; i < CHALF; i += 256) g[i] = gate[b * CC + split * CHALF + i];
    __syncthreads();
    const int n4 = chunk * 256 + tid;   // float4 index within row
    const float4* xb = (const float4*)(x + ((size_t)b * CC + (size_t)split * CHALF) * NN);
    float4 s = {0.f, 0.f, 0.f, 0.f};
    float4 m = {-INFINITY, -INFINITY, -INFINITY, -INFINITY};
    #pragma unroll 4
    for (int c = 0; c < CHALF; ++c) {
        float4 v = xb[(size_t)c * (NN / 4) + n4];
        float gc = g[c];
        s.x = fmaf(gc, v.x, s.x);
        s.y = fmaf(gc, v.y, s.y);
        s.z = fmaf(gc, v.z, s.z);
        s.w = fmaf(gc, v.w, s.w);
        m.x = fmaxf(m.x, gc * v.x);
        m.y = fmaxf(m.y, gc * v.y);
        m.z = fmaxf(m.z, gc * v.z);
        m.w = fmaxf(m.w, gc * v.w);
    }
    const size_t o = (size_t)(b * SPLIT + split) * (NN / 4) + n4;
    ((float4*)psum)[o] = s;
    ((float4*)pmax)[o] = m;
}

// ---------------- K5: s = relu(BN(sw0*cx + sw1*cm)); softmax over N ----------------
__global__ __launch_bounds__(256) void k5_softmax(const float* __restrict__ psum,
                                                  const float* __restrict__ pmax,
                                                  const float* __restrict__ sw,
                                                  const float* __restrict__ gamma,
                                                  const float* __restrict__ beta,
                                                  const float* __restrict__ rmean,
                                                  const float* __restrict__ rvar,
                                                  float* __restrict__ attexp,
                                                  float* __restrict__ invsum) {
    const int b = blockIdx.x;
    const int tid = threadIdx.x;
    const float sw0 = sw[0], sw1 = sw[1];
    const float scale = gamma[0] / sqrtf(rvar[0] + 1e-5f);
    const float shift = beta[0] - rmean[0] * scale;
    const float4* ps0 = (const float4*)(psum + (size_t)(2 * b) * NN);
    const float4* ps1 = (const float4*)(psum + (size_t)(2 * b + 1) * NN);
    const float4* pm0 = (const float4*)(pmax + (size_t)(2 * b) * NN);
    const float4* pm1 = (const float4*)(pmax + (size_t)(2 * b + 1) * NN);

    __shared__ float red[4];
    __shared__ float bcast;

    auto sval = [&](float ssum, float smax) -> float {
        float v = sw0 * smax + sw1 * (ssum * (1.0f / CC));
        v = fmaf(v, scale, shift);
        return fmaxf(v, 0.f);
    };

    float lmax = -INFINITY;
    for (int i = tid; i < NN / 4; i += 256) {
        float4 s0 = ps0[i], s1 = ps1[i], m0 = pm0[i], m1 = pm1[i];
        lmax = fmaxf(lmax, sval(s0.x + s1.x, fmaxf(m0.x, m1.x)));
        lmax = fmaxf(lmax, sval(s0.y + s1.y, fmaxf(m0.y, m1.y)));
        lmax = fmaxf(lmax, sval(s0.z + s1.z, fmaxf(m0.z, m1.z)));
        lmax = fmaxf(lmax, sval(s0.w + s1.w, fmaxf(m0.w, m1.w)));
    }
    for (int off = 32; off > 0; off >>= 1) lmax = fmaxf(lmax, __shfl_down(lmax, off, 64));
    if ((tid & 63) == 0) red[tid >> 6] = lmax;
    __syncthreads();
    if (tid == 0) bcast = fmaxf(fmaxf(red[0], red[1]), fmaxf(red[2], red[3]));
    __syncthreads();
    const float bmax = bcast;
    __syncthreads();

    float lsum = 0.f;
    float4* ae = (float4*)(attexp + (size_t)b * NN);
    for (int i = tid; i < NN / 4; i += 256) {
        float4 s0 = ps0[i], s1 = ps1[i], m0 = pm0[i], m1 = pm1[i];
        float4 e;
        e.x = expf(sval(s0.x + s1.x, fmaxf(m0.x, m1.x)) - bmax);
        e.y = expf(sval(s0.y + s1.y, fmaxf(m0.y, m1.y)) - bmax);
        e.z = expf(sval(s0.z + s1.z, fmaxf(m0.z, m1.z)) - bmax);
        e.w = expf(sval(s0.w + s1.w, fmaxf(m0.w, m1.w)) - bmax);
        lsum += e.x + e.y + e.z + e.w;
        ae[i] = e;
    }
    for (int off = 32; off > 0; off >>= 1) lsum += __shfl_down(lsum, off, 64);
    if ((tid & 63) == 0) red[tid >> 6] = lsum;
    __syncthreads();
    if (tid == 0) invsum[b] = 1.0f / (red[0] + red[1] + red[2] + red[3]);
}

// ---------------- K6: out = att * gate * x ----------------
__global__ __launch_bounds__(256) void k6_final(const float* __restrict__ x,
                                                const float* __restrict__ gate,
                                                const float* __restrict__ attexp,
                                                const float* __restrict__ invsum,
                                                float* __restrict__ out) {
    const int blk = blockIdx.x;          // (b*C + c)*16 + t
    const int t = blk & 15;
    const int row = blk >> 4;            // b*C + c
    const int b = row >> 10;
    const int tid = threadIdx.x;
    const float gsc = gate[row] * invsum[b];
    const size_t base4 = (size_t)row * (NN / 4) + t * 256 + tid;
    const size_t abase4 = (size_t)b * (NN / 4) + t * 256 + tid;
    float4 v = ((const float4*)x)[base4];
    float4 a = ((const float4*)attexp)[abase4];
    float4 o;
    o.x = v.x * a.x * gsc;
    o.y = v.y * a.y * gsc;
    o.z = v.z * a.z * gsc;
    o.w = v.w * a.w * gsc;
    ((float4*)out)[base4] = o;
}

extern "C" void kernel_launch(void* const* d_in, const int* in_sizes, int n_in,
                              void* d_out, int out_size, void* d_ws, size_t ws_size,
                              hipStream_t stream) {
    const float* x     = (const float*)d_in[0];
    const float* w1    = (const float*)d_in[1];
    const float* w2    = (const float*)d_in[2];
    const float* sw    = (const float*)d_in[3];
    const float* gamma = (const float*)d_in[4];
    const float* beta  = (const float*)d_in[5];
    const float* rmean = (const float*)d_in[6];
    const float* rvar  = (const float*)d_in[7];
    float* out = (float*)d_out;
    float* ws  = (float*)d_ws;

    float* meanp  = ws;                       // 16384
    float* maxp   = ws + 16384;               // 16384
    float* gate   = ws + 32768;               // 16384
    float* psum   = ws + 49152;               // B*SPLIT*N = 524288
    float* pmax   = psum + (size_t)BB * SPLIT * NN;   // 524288
    float* attexp = pmax + (size_t)BB * SPLIT * NN;   // B*N = 262144
    float* invsum = attexp + (size_t)BB * NN;         // 16

    k1_pool<<<BB * CC, 256, 0, stream>>>(x, meanp, maxp);
    k2_gate<<<BB, 256, 0, stream>>>(meanp, maxp, w1, w2, gate);
    dim3 g3(NN / 1024, SPLIT, BB);
    k3_spatial<<<g3, 256, 0, stream>>>(x, gate, psum, pmax);
    k5_softmax<<<BB, 256, 0, stream>>>(psum, pmax, sw, gamma, beta, rmean, rvar, attexp, invsum);
    k6_final<<<BB * CC * (NN / 1024), 256, 0, stream>>>(x, gate, attexp, invsum, out);
}

// Round 2
// 810.952 us; speedup vs baseline: 1.0027x; 1.0027x over previous
//
#include <hip/hip_runtime.h>
#include <math.h>

#define BB 16
#define CC 1024
#define NN 16384
#define HID 128         // C / RATIO
#define SPLIT 4
#define CPART (CC/SPLIT)   // 256
#define N4 (NN/4)          // 4096 float4 per row
#define EXPSHIFT 10.0f     // uniform shift inside softmax (exact math)

// ---------------- K1: per-(b,c) mean & max over N ----------------
__global__ __launch_bounds__(256) void k1_pool(const float* __restrict__ x,
                                               float* __restrict__ meanp,
                                               float* __restrict__ maxp) {
    const int row = blockIdx.x;                 // b*C + c
    const int tid = threadIdx.x;
    const float4* xr = (const float4*)(x + (size_t)row * NN);
    float s = 0.f, m = -INFINITY;
    #pragma unroll
    for (int i = 0; i < 16; ++i) {
        float4 v = xr[tid + i * 256];
        s += v.x + v.y + v.z + v.w;
        m = fmaxf(m, fmaxf(fmaxf(v.x, v.y), fmaxf(v.z, v.w)));
    }
    __shared__ float ss[4], sm[4];
    for (int off = 32; off > 0; off >>= 1) {
        s += __shfl_down(s, off, 64);
        m = fmaxf(m, __shfl_down(m, off, 64));
    }
    const int wave = tid >> 6, lane = tid & 63;
    if (lane == 0) { ss[wave] = s; sm[wave] = m; }
    __syncthreads();
    if (tid == 0) {
        float fs = ss[0] + ss[1] + ss[2] + ss[3];
        float fm = fmaxf(fmaxf(sm[0], sm[1]), fmaxf(sm[2], sm[3]));
        meanp[row] = fs * (1.0f / NN);
        maxp[row]  = fm;
    }
}

// ---------------- K2: shared MLP -> gate (1024 threads, 4-way split dots) ----------------
__global__ __launch_bounds__(1024) void k2_gate(const float* __restrict__ meanp,
                                                const float* __restrict__ maxp,
                                                const float* __restrict__ w1,
                                                const float* __restrict__ w2,
                                                float* __restrict__ gate) {
    const int b = blockIdx.x;
    const int tid = threadIdx.x;
    __shared__ float sv[2][CC];
    __shared__ float hh[2][HID];
    __shared__ float h[HID];
    if (tid < CC) {
        sv[0][tid] = meanp[b * CC + tid];
        sv[1][tid] = maxp[b * CC + tid];
    }
    __syncthreads();
    {
        const int slot = tid >> 2;       // 0..255
        const int part = tid & 3;        // 0..3
        const int src  = slot >> 7;      // 0..1
        const int r    = slot & 127;
        const float* w1r = w1 + (size_t)r * CC;
        const float* svp = sv[src];
        float acc = 0.f;
        const int c0 = part * 256;
        #pragma unroll 8
        for (int c = c0; c < c0 + 256; ++c) acc = fmaf(w1r[c], svp[c], acc);
        acc += __shfl_xor(acc, 1, 64);
        acc += __shfl_xor(acc, 2, 64);
        if (part == 0) hh[src][r] = fmaxf(acc, 0.f);   // relu
    }
    __syncthreads();
    if (tid < HID) h[tid] = hh[0][tid] + hh[1][tid];
    __syncthreads();
    {
        const float* w2r = w2 + (size_t)tid * HID;
        float a = 0.f;
        #pragma unroll
        for (int r = 0; r < HID; ++r) a = fmaf(w2r[r], h[r], a);
        gate[b * CC + tid] = 1.0f / (1.0f + expf(-a));  // sigmoid
    }
}

// ---------------- K3: spatial weighted sum/max over C (partials, SPLIT=4) ----------------
__global__ __launch_bounds__(256) void k3_spatial(const float* __restrict__ x,
                                                  const float* __restrict__ gate,
                                                  float* __restrict__ psum,
                                                  float* __restrict__ pmax) {
    const int chunk = blockIdx.x;   // 0..15
    const int split = blockIdx.y;   // 0..SPLIT-1
    const int b     = blockIdx.z;   // 0..B-1
    const int tid = threadIdx.x;
    __shared__ float g[CPART];
    g[tid] = gate[b * CC + split * CPART + tid];
    __syncthreads();
    const int n4 = chunk * 256 + tid;   // float4 index within row
    const float4* xb = (const float4*)(x + ((size_t)b * CC + (size_t)split * CPART) * NN);
    float4 s = {0.f, 0.f, 0.f, 0.f};
    float4 m = {-INFINITY, -INFINITY, -INFINITY, -INFINITY};
    #pragma unroll 8
    for (int c = 0; c < CPART; ++c) {
        float4 v = xb[(size_t)c * N4 + n4];
        float gc = g[c];
        s.x = fmaf(gc, v.x, s.x);
        s.y = fmaf(gc, v.y, s.y);
        s.z = fmaf(gc, v.z, s.z);
        s.w = fmaf(gc, v.w, s.w);
        m.x = fmaxf(m.x, gc * v.x);
        m.y = fmaxf(m.y, gc * v.y);
        m.z = fmaxf(m.z, gc * v.z);
        m.w = fmaxf(m.w, gc * v.w);
    }
    const size_t o = (size_t)(b * SPLIT + split) * N4 + n4;
    ((float4*)psum)[o] = s;
    ((float4*)pmax)[o] = m;
}

// ---------------- K4: s = relu(BN(sw0*cx+sw1*cm)); exp(s-10); partial sums ----------------
__global__ __launch_bounds__(256) void k4_exp(const float* __restrict__ psum,
                                              const float* __restrict__ pmax,
                                              const float* __restrict__ sw,
                                              const float* __restrict__ gamma,
                                              const float* __restrict__ beta,
                                              const float* __restrict__ rmean,
                                              const float* __restrict__ rvar,
                                              float* __restrict__ attexp,
                                              float* __restrict__ blksum) {
    const int chunk = blockIdx.x;   // 0..15
    const int b     = blockIdx.y;
    const int tid = threadIdx.x;
    const float sw0 = sw[0], sw1 = sw[1];
    const float scale = gamma[0] * rsqrtf(rvar[0] + 1e-5f);
    const float shift = beta[0] - rmean[0] * scale;
    const int i = chunk * 256 + tid;    // float4 index in 0..4095
    const float4* ps = (const float4*)psum;
    const float4* pm = (const float4*)pmax;
    float4 ssum = {0.f, 0.f, 0.f, 0.f};
    float4 smax = {-INFINITY, -INFINITY, -INFINITY, -INFINITY};
    #pragma unroll
    for (int sp = 0; sp < SPLIT; ++sp) {
        float4 a = ps[(size_t)(b * SPLIT + sp) * N4 + i];
        float4 c = pm[(size_t)(b * SPLIT + sp) * N4 + i];
        ssum.x += a.x; ssum.y += a.y; ssum.z += a.z; ssum.w += a.w;
        smax.x = fmaxf(smax.x, c.x); smax.y = fmaxf(smax.y, c.y);
        smax.z = fmaxf(smax.z, c.z); smax.w = fmaxf(smax.w, c.w);
    }
    auto sval = [&](float su, float mx) -> float {
        float v = sw0 * mx + sw1 * (su * (1.0f / CC));
        v = fmaf(v, scale, shift);
        v = fmaxf(v, 0.f);                 // relu
        return expf(v - EXPSHIFT);
    };
    float4 e;
    e.x = sval(ssum.x, smax.x);
    e.y = sval(ssum.y, smax.y);
    e.z = sval(ssum.z, smax.z);
    e.w = sval(ssum.w, smax.w);
    ((float4*)attexp)[(size_t)b * N4 + i] = e;
    float lsum = e.x + e.y + e.z + e.w;
    for (int off = 32; off > 0; off >>= 1) lsum += __shfl_down(lsum, off, 64);
    __shared__ float red[4];
    if ((tid & 63) == 0) red[tid >> 6] = lsum;
    __syncthreads();
    if (tid == 0) blksum[b * 16 + chunk] = red[0] + red[1] + red[2] + red[3];
}

// ---------------- K6: out = attexp/sum * gate * x ----------------
__global__ __launch_bounds__(256) void k6_final(const float* __restrict__ x,
                                                const float* __restrict__ gate,
                                                const float* __restrict__ attexp,
                                                const float* __restrict__ blksum,
                                                float* __restrict__ out) {
    const int blk = blockIdx.x;          // (b*C + c)*4 + t
    const int t = blk & 3;
    const int row = blk >> 2;            // b*C + c
    const int b = row >> 10;
    const int tid = threadIdx.x;
    float tot = 0.f;
    #pragma unroll
    for (int j = 0; j < 16; ++j) tot += blksum[b * 16 + j];
    const float gsc = gate[row] / tot;
    const size_t base4  = (size_t)row * N4 + t * 1024 + tid;
    const size_t abase4 = (size_t)b * N4 + t * 1024 + tid;
    const float4* xp = (const float4*)x;
    const float4* ap = (const float4*)attexp;
    float4* op = (float4*)out;
    #pragma unroll
    for (int j = 0; j < 4; ++j) {
        float4 v = xp[base4 + j * 256];
        float4 a = ap[abase4 + j * 256];
        float4 o;
        o.x = v.x * a.x * gsc;
        o.y = v.y * a.y * gsc;
        o.z = v.z * a.z * gsc;
        o.w = v.w * a.w * gsc;
        op[base4 + j * 256] = o;
    }
}

extern "C" void kernel_launch(void* const* d_in, const int* in_sizes, int n_in,
                              void* d_out, int out_size, void* d_ws, size_t ws_size,
                              hipStream_t stream) {
    const float* x     = (const float*)d_in[0];
    const float* w1    = (const float*)d_in[1];
    const float* w2    = (const float*)d_in[2];
    const float* sw    = (const float*)d_in[3];
    const float* gamma = (const float*)d_in[4];
    const float* beta  = (const float*)d_in[5];
    const float* rmean = (const float*)d_in[6];
    const float* rvar  = (const float*)d_in[7];
    float* out = (float*)d_out;
    float* ws  = (float*)d_ws;

    float* meanp  = ws;                                  // 16384
    float* maxp   = meanp + 16384;                       // 16384
    float* gate   = maxp + 16384;                        // 16384
    float* psum   = gate + 16384;                        // B*SPLIT*N = 1048576
    float* pmax   = psum + (size_t)BB * SPLIT * NN;      // 1048576
    float* attexp = pmax + (size_t)BB * SPLIT * NN;      // B*N = 262144
    float* blksum = attexp + (size_t)BB * NN;            // 256

    k1_pool<<<BB * CC, 256, 0, stream>>>(x, meanp, maxp);
    k2_gate<<<BB, 1024, 0, stream>>>(meanp, maxp, w1, w2, gate);
    dim3 g3(NN / 1024, SPLIT, BB);
    k3_spatial<<<g3, 256, 0, stream>>>(x, gate, psum, pmax);
    dim3 g4(16, BB);
    k4_exp<<<g4, 256, 0, stream>>>(psum, pmax, sw, gamma, beta, rmean, rvar, attexp, blksum);
    k6_final<<<BB * CC * 4, 256, 0, stream>>>(x, gate, attexp, blksum, out);
}

// Round 4
// 758.790 us; speedup vs baseline: 1.0717x; 1.0687x over previous
//
#include <hip/hip_runtime.h>
#include <math.h>

#define BB 16
#define CC 1024
#define NN 16384
#define HID 128            // C / RATIO
#define SPLIT 4
#define CPART (CC/SPLIT)   // 256
#define N4 (NN/4)          // 4096 float4 per row
#define EXPSHIFT 10.0f     // uniform shift inside softmax (exact math)
#define CG 8               // c-rows per block in k6

typedef float f4 __attribute__((ext_vector_type(4)));   // native vector for nontemporal builtins

// ---------------- K1: per-(b,c) mean & max over N ----------------
__global__ __launch_bounds__(256) void k1_pool(const float* __restrict__ x,
                                               float* __restrict__ meanp,
                                               float* __restrict__ maxp) {
    const int row = blockIdx.x;                 // b*C + c
    const int tid = threadIdx.x;
    const f4* xr = (const f4*)(x + (size_t)row * NN);
    float s = 0.f, m = -INFINITY;
    #pragma unroll
    for (int i = 0; i < 16; ++i) {
        f4 v = __builtin_nontemporal_load(&xr[tid + i * 256]);
        s += v.x + v.y + v.z + v.w;
        m = fmaxf(m, fmaxf(fmaxf(v.x, v.y), fmaxf(v.z, v.w)));
    }
    __shared__ float ss[4], sm[4];
    for (int off = 32; off > 0; off >>= 1) {
        s += __shfl_down(s, off, 64);
        m = fmaxf(m, __shfl_down(m, off, 64));
    }
    const int wave = tid >> 6, lane = tid & 63;
    if (lane == 0) { ss[wave] = s; sm[wave] = m; }
    __syncthreads();
    if (tid == 0) {
        float fs = ss[0] + ss[1] + ss[2] + ss[3];
        float fm = fmaxf(fmaxf(sm[0], sm[1]), fmaxf(sm[2], sm[3]));
        meanp[row] = fs * (1.0f / NN);
        maxp[row]  = fm;
    }
}

// ---------------- K2: shared MLP -> gate (1024 threads, 4-way split dots) ----------------
__global__ __launch_bounds__(1024) void k2_gate(const float* __restrict__ meanp,
                                                const float* __restrict__ maxp,
                                                const float* __restrict__ w1,
                                                const float* __restrict__ w2,
                                                float* __restrict__ gate) {
    const int b = blockIdx.x;
    const int tid = threadIdx.x;
    __shared__ float sv[2][CC];
    __shared__ float hh[2][HID];
    __shared__ float h[HID];
    if (tid < CC) {
        sv[0][tid] = meanp[b * CC + tid];
        sv[1][tid] = maxp[b * CC + tid];
    }
    __syncthreads();
    {
        const int slot = tid >> 2;       // 0..255
        const int part = tid & 3;        // 0..3
        const int src  = slot >> 7;      // 0..1
        const int r    = slot & 127;
        const float* w1r = w1 + (size_t)r * CC;
        const float* svp = sv[src];
        float acc = 0.f;
        const int c0 = part * 256;
        #pragma unroll 8
        for (int c = c0; c < c0 + 256; ++c) acc = fmaf(w1r[c], svp[c], acc);
        acc += __shfl_xor(acc, 1, 64);
        acc += __shfl_xor(acc, 2, 64);
        if (part == 0) hh[src][r] = fmaxf(acc, 0.f);   // relu
    }
    __syncthreads();
    if (tid < HID) h[tid] = hh[0][tid] + hh[1][tid];
    __syncthreads();
    {
        const float* w2r = w2 + (size_t)tid * HID;
        float a = 0.f;
        #pragma unroll
        for (int r = 0; r < HID; ++r) a = fmaf(w2r[r], h[r], a);
        gate[b * CC + tid] = 1.0f / (1.0f + expf(-a));  // sigmoid
    }
}

// ---------------- K3: spatial weighted sum/max over C (partials, SPLIT=4) ----------------
__global__ __launch_bounds__(256) void k3_spatial(const float* __restrict__ x,
                                                  const float* __restrict__ gate,
                                                  float* __restrict__ psum,
                                                  float* __restrict__ pmax) {
    const int chunk = blockIdx.x;   // 0..15
    const int split = blockIdx.y;   // 0..SPLIT-1
    const int b     = blockIdx.z;   // 0..B-1
    const int tid = threadIdx.x;
    __shared__ float g[CPART];
    g[tid] = gate[b * CC + split * CPART + tid];
    __syncthreads();
    const int n4 = chunk * 256 + tid;   // float4 index within row
    const f4* xb = (const f4*)(x + ((size_t)b * CC + (size_t)split * CPART) * NN);
    f4 s = {0.f, 0.f, 0.f, 0.f};
    f4 m = {-INFINITY, -INFINITY, -INFINITY, -INFINITY};
    #pragma unroll 16
    for (int c = 0; c < CPART; ++c) {
        f4 v = __builtin_nontemporal_load(&xb[(size_t)c * N4 + n4]);
        float gc = g[c];
        s.x = fmaf(gc, v.x, s.x);
        s.y = fmaf(gc, v.y, s.y);
        s.z = fmaf(gc, v.z, s.z);
        s.w = fmaf(gc, v.w, s.w);
        m.x = fmaxf(m.x, gc * v.x);
        m.y = fmaxf(m.y, gc * v.y);
        m.z = fmaxf(m.z, gc * v.z);
        m.w = fmaxf(m.w, gc * v.w);
    }
    const size_t o = (size_t)(b * SPLIT + split) * N4 + n4;
    ((f4*)psum)[o] = s;
    ((f4*)pmax)[o] = m;
}

// ---------------- K4: s = relu(BN(sw0*cx+sw1*cm)); exp(s-10); partial sums ----------------
__global__ __launch_bounds__(256) void k4_exp(const float* __restrict__ psum,
                                              const float* __restrict__ pmax,
                                              const float* __restrict__ sw,
                                              const float* __restrict__ gamma,
                                              const float* __restrict__ beta,
                                              const float* __restrict__ rmean,
                                              const float* __restrict__ rvar,
                                              float* __restrict__ attexp,
                                              float* __restrict__ blksum) {
    const int chunk = blockIdx.x;   // 0..15
    const int b     = blockIdx.y;
    const int tid = threadIdx.x;
    const float sw0 = sw[0], sw1 = sw[1];
    const float scale = gamma[0] * rsqrtf(rvar[0] + 1e-5f);
    const float shift = beta[0] - rmean[0] * scale;
    const int i = chunk * 256 + tid;    // float4 index in 0..4095
    const f4* ps = (const f4*)psum;
    const f4* pm = (const f4*)pmax;
    f4 ssum = {0.f, 0.f, 0.f, 0.f};
    f4 smax = {-INFINITY, -INFINITY, -INFINITY, -INFINITY};
    #pragma unroll
    for (int sp = 0; sp < SPLIT; ++sp) {
        f4 a = ps[(size_t)(b * SPLIT + sp) * N4 + i];
        f4 c = pm[(size_t)(b * SPLIT + sp) * N4 + i];
        ssum.x += a.x; ssum.y += a.y; ssum.z += a.z; ssum.w += a.w;
        smax.x = fmaxf(smax.x, c.x); smax.y = fmaxf(smax.y, c.y);
        smax.z = fmaxf(smax.z, c.z); smax.w = fmaxf(smax.w, c.w);
    }
    auto sval = [&](float su, float mx) -> float {
        float v = sw0 * mx + sw1 * (su * (1.0f / CC));
        v = fmaf(v, scale, shift);
        v = fmaxf(v, 0.f);                 // relu
        return expf(v - EXPSHIFT);
    };
    f4 e;
    e.x = sval(ssum.x, smax.x);
    e.y = sval(ssum.y, smax.y);
    e.z = sval(ssum.z, smax.z);
    e.w = sval(ssum.w, smax.w);
    ((f4*)attexp)[(size_t)b * N4 + i] = e;
    float lsum = e.x + e.y + e.z + e.w;
    for (int off = 32; off > 0; off >>= 1) lsum += __shfl_down(lsum, off, 64);
    __shared__ float red[4];
    if ((tid & 63) == 0) red[tid >> 6] = lsum;
    __syncthreads();
    if (tid == 0) blksum[b * 16 + chunk] = red[0] + red[1] + red[2] + red[3];
}

// ---------------- K5: per-row scale = gate[row] / sum_b ----------------
__global__ __launch_bounds__(256) void k5_gscale(const float* __restrict__ gate,
                                                 const float* __restrict__ blksum,
                                                 float* __restrict__ gscale) {
    const int row = blockIdx.x * 256 + threadIdx.x;   // 0..16383
    const int b = row >> 10;
    float tot = 0.f;
    #pragma unroll
    for (int j = 0; j < 16; ++j) tot += blksum[b * 16 + j];
    gscale[row] = gate[row] / tot;
}

// ---------------- K6: out = attexp * gscale * x (CG rows share attexp) ----------------
__global__ __launch_bounds__(256) void k6_final(const float* __restrict__ x,
                                                const float* __restrict__ gscale,
                                                const float* __restrict__ attexp,
                                                float* __restrict__ out) {
    const int chunk = blockIdx.x;      // 0..15  (n-chunk of 256 float4)
    const int cgrp  = blockIdx.y;      // 0..CC/CG-1
    const int b     = blockIdx.z;      // 0..BB-1
    const int tid = threadIdx.x;
    const int n4 = chunk * 256 + tid;
    const int row0 = b * CC + cgrp * CG;
    const f4 a = ((const f4*)attexp)[(size_t)b * N4 + n4];
    float gs[CG];
    #pragma unroll
    for (int r = 0; r < CG; ++r) gs[r] = gscale[row0 + r];
    const f4* xp = (const f4*)x;
    f4* op = (f4*)out;
    f4 v[CG];
    #pragma unroll
    for (int r = 0; r < CG; ++r)
        v[r] = __builtin_nontemporal_load(&xp[(size_t)(row0 + r) * N4 + n4]);
    #pragma unroll
    for (int r = 0; r < CG; ++r) {
        f4 o;
        o.x = v[r].x * a.x * gs[r];
        o.y = v[r].y * a.y * gs[r];
        o.z = v[r].z * a.z * gs[r];
        o.w = v[r].w * a.w * gs[r];
        __builtin_nontemporal_store(o, &op[(size_t)(row0 + r) * N4 + n4]);
    }
}

extern "C" void kernel_launch(void* const* d_in, const int* in_sizes, int n_in,
                              void* d_out, int out_size, void* d_ws, size_t ws_size,
                              hipStream_t stream) {
    const float* x     = (const float*)d_in[0];
    const float* w1    = (const float*)d_in[1];
    const float* w2    = (const float*)d_in[2];
    const float* sw    = (const float*)d_in[3];
    const float* gamma = (const float*)d_in[4];
    const float* beta  = (const float*)d_in[5];
    const float* rmean = (const float*)d_in[6];
    const float* rvar  = (const float*)d_in[7];
    float* out = (float*)d_out;
    float* ws  = (float*)d_ws;

    float* meanp  = ws;                                  // 16384
    float* maxp   = meanp + 16384;                       // 16384
    float* gate   = maxp + 16384;                        // 16384
    float* gscale = gate + 16384;                        // 16384
    float* psum   = gscale + 16384;                      // B*SPLIT*N = 1048576
    float* pmax   = psum + (size_t)BB * SPLIT * NN;      // 1048576
    float* attexp = pmax + (size_t)BB * SPLIT * NN;      // B*N = 262144
    float* blksum = attexp + (size_t)BB * NN;            // 256

    k1_pool<<<BB * CC, 256, 0, stream>>>(x, meanp, maxp);
    k2_gate<<<BB, 1024, 0, stream>>>(meanp, maxp, w1, w2, gate);
    dim3 g3(NN / 1024, SPLIT, BB);
    k3_spatial<<<g3, 256, 0, stream>>>(x, gate, psum, pmax);
    dim3 g4(16, BB);
    k4_exp<<<g4, 256, 0, stream>>>(psum, pmax, sw, gamma, beta, rmean, rvar, attexp, blksum);
    k5_gscale<<<BB * CC / 256, 256, 0, stream>>>(gate, blksum, gscale);
    dim3 g6(16, CC / CG, BB);
    k6_final<<<g6, 256, 0, stream>>>(x, gscale, attexp, out);
}